// Round 1
// baseline (41.539 us; speedup 1.0000x reference)
//
#include <hip/hip_runtime.h>

// 8x8 orthonormal DCT-II matrix, hardcoded.
// a_k = 0.5*cos(k*pi/16), c4 = sqrt(1/8)
#define A1 0.4903926402f
#define A3 0.4157348061f
#define A5 0.2777851165f
#define A7 0.0975451610f
#define B2 0.4619397663f
#define B6 0.1913417162f
#define C4 0.3535533906f

__device__ __constant__ float Dc[8][8] = {
    { C4,  C4,  C4,  C4,  C4,  C4,  C4,  C4},
    { A1,  A3,  A5,  A7, -A7, -A5, -A3, -A1},
    { B2,  B6, -B6, -B2, -B2, -B6,  B6,  B2},
    { A3, -A7, -A1, -A5,  A5,  A1,  A7, -A3},
    { C4, -C4, -C4,  C4,  C4, -C4, -C4,  C4},
    { A5, -A1,  A7,  A3, -A3, -A7,  A1, -A5},
    { B6, -B2,  B2, -B6, -B6,  B2, -B2,  B6},
    { A7, -A5,  A3, -A1,  A1, -A3,  A5, -A7},
};

#define IMG_W 512

__global__ __launch_bounds__(256) void dct8x8_kernel(const float* __restrict__ x,
                                                     float* __restrict__ y,
                                                     int total_blocks) {
    int t = blockIdx.x * blockDim.x + threadIdx.x;
    if (t >= total_blocks) return;

    // 512x512 plane = 64x64 blocks of 8x8
    int plane = t >> 12;       // / 4096
    int blk   = t & 4095;
    int br    = blk >> 6;      // block row
    int bc    = blk & 63;      // block col (consecutive threads -> consecutive cols)

    const size_t base = (size_t)plane * (IMG_W * IMG_W)
                      + (size_t)br * 8 * IMG_W
                      + (size_t)bc * 8;
    const float* __restrict__ src = x + base;
    float*       __restrict__ dst = y + base;

    float X[8][8];
#pragma unroll
    for (int r = 0; r < 8; ++r) {
        float4 a = *reinterpret_cast<const float4*>(src + r * IMG_W);
        float4 b = *reinterpret_cast<const float4*>(src + r * IMG_W + 4);
        X[r][0] = a.x; X[r][1] = a.y; X[r][2] = a.z; X[r][3] = a.w;
        X[r][4] = b.x; X[r][5] = b.y; X[r][6] = b.z; X[r][7] = b.w;
    }

    // Stage 1: T = D @ X   (column transform)
    float T[8][8];
#pragma unroll
    for (int i = 0; i < 8; ++i) {
#pragma unroll
        for (int k = 0; k < 8; ++k) {
            float s = 0.0f;
#pragma unroll
            for (int j = 0; j < 8; ++j) s = fmaf(Dc[i][j], X[j][k], s);
            T[i][k] = s;
        }
    }

    // Stage 2: O = T @ D^T, store row by row
#pragma unroll
    for (int i = 0; i < 8; ++i) {
        float o[8];
#pragma unroll
        for (int l = 0; l < 8; ++l) {
            float s = 0.0f;
#pragma unroll
            for (int k = 0; k < 8; ++k) s = fmaf(T[i][k], Dc[l][k], s);
            o[l] = s;
        }
        float4 a = {o[0], o[1], o[2], o[3]};
        float4 b = {o[4], o[5], o[6], o[7]};
        *reinterpret_cast<float4*>(dst + i * IMG_W)     = a;
        *reinterpret_cast<float4*>(dst + i * IMG_W + 4) = b;
    }
}

extern "C" void kernel_launch(void* const* d_in, const int* in_sizes, int n_in,
                              void* d_out, int out_size, void* d_ws, size_t ws_size,
                              hipStream_t stream) {
    const float* x = (const float*)d_in[0];
    float* y = (float*)d_out;

    const int total_blocks = out_size / 64;  // 393216 for 32*3*512*512
    const int threads = 256;
    const int grid = (total_blocks + threads - 1) / threads;

    dct8x8_kernel<<<grid, threads, 0, stream>>>(x, y, total_blocks);
}

// Round 2
// 39.000 us; speedup vs baseline: 1.0651x; 1.0651x over previous
//
#include <hip/hip_runtime.h>

// 8x8 orthonormal DCT-II matrix, hardcoded.
// a_k = 0.5*cos(k*pi/16), c4 = sqrt(1/8)
#define A1 0.4903926402f
#define A3 0.4157348061f
#define A5 0.2777851165f
#define A7 0.0975451610f
#define B2 0.4619397663f
#define B6 0.1913417162f
#define C4 0.3535533906f

__device__ __constant__ float Dc[8][8] = {
    { C4,  C4,  C4,  C4,  C4,  C4,  C4,  C4},
    { A1,  A3,  A5,  A7, -A7, -A5, -A3, -A1},
    { B2,  B6, -B6, -B2, -B2, -B6,  B6,  B2},
    { A3, -A7, -A1, -A5,  A5,  A1,  A7, -A3},
    { C4, -C4, -C4,  C4,  C4, -C4, -C4,  C4},
    { A5, -A1,  A7,  A3, -A3, -A7,  A1, -A5},
    { B6, -B2,  B2, -B6, -B6,  B2, -B2,  B6},
    { A7, -A5,  A3, -A1,  A1, -A3,  A5, -A7},
};

#define IMG_W 512
// LDS: indexed [(c*32 + blk)*9 + r] — stride 9 (coprime with 32 banks)
// makes every scalar LDS access <=2-way bank-aliased (free on CDNA4).
#define LDS_FLOATS (8 * 32 * 9)

// One workgroup = 32 consecutive 8x8 blocks (256x8 pixel strip).
// One thread = one row (phases 1/4) or one column (phases 2/3) of one block.
__global__ __launch_bounds__(256, 8) void dct8x8_kernel(const float* __restrict__ x,
                                                        float* __restrict__ y) {
    __shared__ float lds[LDS_FLOATS];

    const int t   = threadIdx.x;
    const int blk = t & 31;   // block index within the 32-block strip
    const int r8  = t >> 5;   // row (phases 1,4) / column (phases 2,3) index, 0..7

    // Grid: 96 planes * 64 block-rows * 2 strips = 12288 WGs
    const int wg    = blockIdx.x;
    const int plane = wg >> 7;        // / 128
    const int rem   = wg & 127;
    const int ty    = rem >> 1;       // block-row 0..63
    const int tx    = rem & 1;        // strip 0..1

    const size_t base = (size_t)plane * (IMG_W * IMG_W)
                      + (size_t)ty * 8 * IMG_W
                      + (size_t)tx * 256
                      + (size_t)blk * 8;

    // ---- Phase 1: load one row, row-DCT (X @ D^T), scatter to LDS ----
    const float* __restrict__ src = x + base + (size_t)r8 * IMG_W;
    float4 a = *reinterpret_cast<const float4*>(src);
    float4 b = *reinterpret_cast<const float4*>(src + 4);
    float xv[8] = {a.x, a.y, a.z, a.w, b.x, b.y, b.z, b.w};

#pragma unroll
    for (int c = 0; c < 8; ++c) {
        float s = 0.0f;
#pragma unroll
        for (int m = 0; m < 8; ++m) s = fmaf(Dc[c][m], xv[m], s);
        lds[(c * 32 + blk) * 9 + r8] = s;
    }
    __syncthreads();

    // ---- Phase 2: read one column, column-DCT (D @ T) ----
    const int c = r8;
    float z[8];
#pragma unroll
    for (int r = 0; r < 8; ++r) z[r] = lds[(c * 32 + blk) * 9 + r];

    float w[8];
#pragma unroll
    for (int i = 0; i < 8; ++i) {
        float s = 0.0f;
#pragma unroll
        for (int r = 0; r < 8; ++r) s = fmaf(Dc[i][r], z[r], s);
        w[i] = s;
    }
    __syncthreads();   // all phase-2 reads done before overwriting lds

    // ---- Phase 3: scatter transposed result back to LDS ----
#pragma unroll
    for (int i = 0; i < 8; ++i) lds[(i * 32 + blk) * 9 + c] = w[i];
    __syncthreads();

    // ---- Phase 4: gather one output row, store coalesced ----
    float o[8];
#pragma unroll
    for (int cc = 0; cc < 8; ++cc) o[cc] = lds[(r8 * 32 + blk) * 9 + cc];

    float* __restrict__ dst = y + base + (size_t)r8 * IMG_W;
    float4 oa = {o[0], o[1], o[2], o[3]};
    float4 ob = {o[4], o[5], o[6], o[7]};
    *reinterpret_cast<float4*>(dst)     = oa;
    *reinterpret_cast<float4*>(dst + 4) = ob;
}

extern "C" void kernel_launch(void* const* d_in, const int* in_sizes, int n_in,
                              void* d_out, int out_size, void* d_ws, size_t ws_size,
                              hipStream_t stream) {
    const float* x = (const float*)d_in[0];
    float* y = (float*)d_out;

    // Each WG covers 256*8 = 2048 elements.
    const int grid = out_size / 2048;   // 12288 for 32*3*512*512

    dct8x8_kernel<<<grid, 256, 0, stream>>>(x, y);
}

// Round 3
// 38.491 us; speedup vs baseline: 1.0792x; 1.0132x over previous
//
#include <hip/hip_runtime.h>

// 8x8 orthonormal DCT-II matrix, hardcoded.
// a_k = 0.5*cos(k*pi/16), c4 = sqrt(1/8)
#define A1 0.4903926402f
#define A3 0.4157348061f
#define A5 0.2777851165f
#define A7 0.0975451610f
#define B2 0.4619397663f
#define B6 0.1913417162f
#define C4 0.3535533906f

__device__ __constant__ float Dc[8][8] = {
    { C4,  C4,  C4,  C4,  C4,  C4,  C4,  C4},
    { A1,  A3,  A5,  A7, -A7, -A5, -A3, -A1},
    { B2,  B6, -B6, -B2, -B2, -B6,  B6,  B2},
    { A3, -A7, -A1, -A5,  A5,  A1,  A7, -A3},
    { C4, -C4, -C4,  C4,  C4, -C4, -C4,  C4},
    { A5, -A1,  A7,  A3, -A3, -A7,  A1, -A5},
    { B6, -B2,  B2, -B6, -B6,  B2, -B2,  B6},
    { A7, -A5,  A3, -A1,  A1, -A3,  A5, -A7},
};

#define IMG_W 512
// LDS: indexed [(row*32 + blk)*9 + col] — stride 9 (coprime with 32 banks)
// keeps every access pattern <=2-way bank-aliased (free on CDNA4).
#define LDS_FLOATS (8 * 32 * 9)

typedef float v4f __attribute__((ext_vector_type(4)));

// One workgroup = 32 consecutive 8x8 blocks (256x8 pixel strip).
__global__ __launch_bounds__(256, 8) void dct8x8_kernel(const float* __restrict__ x,
                                                        float* __restrict__ y) {
    __shared__ float lds[LDS_FLOATS];

    const int t   = threadIdx.x;
    const int blk = t & 31;   // block index within the 32-block strip
    const int r8  = t >> 5;   // row (phase 1) / column (phases 2,3) index, 0..7

    // Grid: 96 planes * 64 block-rows * 2 strips = 12288 WGs
    const int wg    = blockIdx.x;
    const int plane = wg >> 7;        // / 128
    const int rem   = wg & 127;
    const int ty    = rem >> 1;       // block-row 0..63
    const int tx    = rem & 1;        // strip 0..1

    const size_t sbase = (size_t)plane * (IMG_W * IMG_W)
                       + (size_t)ty * 8 * IMG_W
                       + (size_t)tx * 256;

    // ---- Phase 1: load one row of one block, row-DCT (X @ D^T), scatter to LDS ----
    const float* __restrict__ src = x + sbase + (size_t)r8 * IMG_W + (size_t)blk * 8;
    float4 a = *reinterpret_cast<const float4*>(src);
    float4 b = *reinterpret_cast<const float4*>(src + 4);
    float xv[8] = {a.x, a.y, a.z, a.w, b.x, b.y, b.z, b.w};

#pragma unroll
    for (int c = 0; c < 8; ++c) {
        float s = 0.0f;
#pragma unroll
        for (int m = 0; m < 8; ++m) s = fmaf(Dc[c][m], xv[m], s);
        lds[(c * 32 + blk) * 9 + r8] = s;
    }
    __syncthreads();

    // ---- Phase 2: read one column, column-DCT (D @ T) ----
    const int c = r8;
    float z[8];
#pragma unroll
    for (int r = 0; r < 8; ++r) z[r] = lds[(c * 32 + blk) * 9 + r];

    float w[8];
#pragma unroll
    for (int i = 0; i < 8; ++i) {
        float s = 0.0f;
#pragma unroll
        for (int r = 0; r < 8; ++r) s = fmaf(Dc[i][r], z[r], s);
        w[i] = s;
    }
    __syncthreads();   // all phase-2 reads done before overwriting lds

    // ---- Phase 3: scatter transposed result back to LDS ----
    // lds now holds final outputs in layout [(row*32 + blk)*9 + col]
#pragma unroll
    for (int i = 0; i < 8; ++i) lds[(i * 32 + blk) * 9 + c] = w[i];
    __syncthreads();

    // ---- Phase 4: store-linear gather; each wave store instr = 1KB contiguous ----
    // float4 index f over the strip: row = f>>6, col4 = f&63.
#pragma unroll
    for (int h = 0; h < 2; ++h) {
        const int f    = t + h * 256;
        const int row  = f >> 6;
        const int col4 = f & 63;
        const int blk2 = col4 >> 1;            // 8-col block containing these 4 cols
        const int c0   = (col4 & 1) * 4;       // starting col within block
        const int lb   = (row * 32 + blk2) * 9 + c0;
        v4f o;
        o.x = lds[lb + 0];
        o.y = lds[lb + 1];
        o.z = lds[lb + 2];
        o.w = lds[lb + 3];
        float* dst = y + sbase + (size_t)row * IMG_W + (size_t)col4 * 4;
        __builtin_nontemporal_store(o, reinterpret_cast<v4f*>(dst));
    }
}

extern "C" void kernel_launch(void* const* d_in, const int* in_sizes, int n_in,
                              void* d_out, int out_size, void* d_ws, size_t ws_size,
                              hipStream_t stream) {
    const float* x = (const float*)d_in[0];
    float* y = (float*)d_out;

    // Each WG covers 256*8 = 2048 elements.
    const int grid = out_size / 2048;   // 12288 for 32*3*512*512

    dct8x8_kernel<<<grid, 256, 0, stream>>>(x, y);
}

// Round 4
// 34.857 us; speedup vs baseline: 1.1917x; 1.1042x over previous
//
#include <hip/hip_runtime.h>

typedef float v4f __attribute__((ext_vector_type(4)));

// 8x8 orthonormal DCT-II coefficients: a_k = 0.5*cos(k*pi/16), c4 = sqrt(1/8)
#define A1 0.4903926402f
#define A3 0.4157348061f
#define A5 0.2777851165f
#define A7 0.0975451610f
#define B2 0.4619397663f
#define B6 0.1913417162f
#define C4 0.3535533906f

#define IMG_W 512

// One thread = one vertical half (4 cols x 8 rows) of one 8x8 block.
// Even lane: cols 0-3, odd lane: cols 4-7 of the same block -> lane pairs
// tile memory contiguously (16B per lane), and the row-DCT exchange is a
// single lane^1 shuffle (DPP). No LDS, no barriers: loads stay in flight
// continuously instead of one burst per barrier-phased workgroup.
__global__ __launch_bounds__(256) void dct8x8_kernel(const float* __restrict__ x,
                                                     float* __restrict__ y,
                                                     int nhalf) {
    constexpr float D[8][8] = {
        { C4,  C4,  C4,  C4,  C4,  C4,  C4,  C4},
        { A1,  A3,  A5,  A7, -A7, -A5, -A3, -A1},
        { B2,  B6, -B6, -B2, -B2, -B6,  B6,  B2},
        { A3, -A7, -A1, -A5,  A5,  A1,  A7, -A3},
        { C4, -C4, -C4,  C4,  C4, -C4, -C4,  C4},
        { A5, -A1,  A7,  A3, -A3, -A7,  A1, -A5},
        { B6, -B2,  B2, -B6, -B6,  B2, -B2,  B6},
        { A7, -A5,  A3, -A1,  A1, -A3,  A5, -A7},
    };

    const int t = blockIdx.x * 256 + threadIdx.x;
    if (t >= nhalf) return;

    const int h = t & 1;     // 0: cols 0-3, 1: cols 4-7
    const int g = t >> 1;    // block id
    const int plane = g >> 12;       // 4096 blocks per 512x512 plane
    const int b     = g & 4095;
    const int br    = b >> 6;        // block row 0..63
    const int bc    = b & 63;        // block col 0..63

    const size_t base = (size_t)plane * (IMG_W * IMG_W)
                      + (size_t)br * 8 * IMG_W
                      + (size_t)bc * 8 + (size_t)h * 4;

    // ---- Load 8 rows x 4 cols (128B in flight per thread) ----
    const float* __restrict__ src = x + base;
    float X[8][4];
#pragma unroll
    for (int r = 0; r < 8; ++r) {
        v4f v = *reinterpret_cast<const v4f*>(src + (size_t)r * IMG_W);
        X[r][0] = v.x; X[r][1] = v.y; X[r][2] = v.z; X[r][3] = v.w;
    }

    // Per-lane D columns for the row transform: Dh[jj][m] = D[h*4+jj][m].
    // Both arms are compile-time literals -> folds to cndmask, all static
    // indexing (no scratch).
    float Dh[4][8];
#pragma unroll
    for (int jj = 0; jj < 4; ++jj)
#pragma unroll
        for (int m = 0; m < 8; ++m)
            Dh[jj][m] = h ? D[4 + jj][m] : D[jj][m];

    // ---- Stage 1: column DCT on own 4 columns: T[i][k] = sum_r D[i][r] X[r][k] ----
    float T[8][4];
#pragma unroll
    for (int i = 0; i < 8; ++i)
#pragma unroll
        for (int k = 0; k < 4; ++k) {
            float s = 0.0f;
#pragma unroll
            for (int r = 0; r < 8; ++r) s = fmaf(D[i][r], X[r][k], s);
            T[i][k] = s;
        }

    // ---- Stage 2: row DCT; full row via lane^1 shuffle, own 4 output cols ----
    float* __restrict__ dst = y + base;
#pragma unroll
    for (int i = 0; i < 8; ++i) {
        float r4[4];
#pragma unroll
        for (int kk = 0; kk < 4; ++kk) r4[kk] = __shfl_xor(T[i][kk], 1, 64);

        float lo[4], hi[4];   // full row: cols 0-3 / cols 4-7
#pragma unroll
        for (int kk = 0; kk < 4; ++kk) {
            lo[kk] = h ? r4[kk]   : T[i][kk];
            hi[kk] = h ? T[i][kk] : r4[kk];
        }

        float ov[4];
#pragma unroll
        for (int jj = 0; jj < 4; ++jj) {
            float s = 0.0f;
#pragma unroll
            for (int k = 0; k < 4; ++k) s = fmaf(lo[k], Dh[jj][k],     s);
#pragma unroll
            for (int k = 0; k < 4; ++k) s = fmaf(hi[k], Dh[jj][4 + k], s);
            ov[jj] = s;
        }

        v4f o;
        o.x = ov[0]; o.y = ov[1]; o.z = ov[2]; o.w = ov[3];
        __builtin_nontemporal_store(o, reinterpret_cast<v4f*>(dst + (size_t)i * IMG_W));
    }
}

extern "C" void kernel_launch(void* const* d_in, const int* in_sizes, int n_in,
                              void* d_out, int out_size, void* d_ws, size_t ws_size,
                              hipStream_t stream) {
    const float* x = (const float*)d_in[0];
    float* y = (float*)d_out;

    const int nhalf = out_size / 32;             // 2 threads per 8x8 block
    const int grid  = (nhalf + 255) / 256;       // 3072 WGs

    dct8x8_kernel<<<grid, 256, 0, stream>>>(x, y, nhalf);
}

// Round 5
// 34.698 us; speedup vs baseline: 1.1972x; 1.0046x over previous
//
#include <hip/hip_runtime.h>

typedef float v4f __attribute__((ext_vector_type(4)));

// 8x8 orthonormal DCT-II coefficients: a_k = 0.5*cos(k*pi/16), c4 = sqrt(1/8)
#define A1 0.4903926402f
#define A3 0.4157348061f
#define A5 0.2777851165f
#define A7 0.0975451610f
#define B2 0.4619397663f
#define B6 0.1913417162f
#define C4 0.3535533906f

#define IMG_W 512

// One thread = one vertical half (4 cols x 8 rows) of one 8x8 block,
// TWO blocks per thread (second offset by half the tensor), software-
// pipelined: all 16 row-loads issued before item-0 compute, so item-1's
// HBM latency hides under item-0's stage-2. Lane pairs (h=0/1) tile
// memory contiguously; row exchange is a lane^1 shuffle. No LDS.
__global__ __launch_bounds__(256) void dct8x8_kernel(const float* __restrict__ x,
                                                     float* __restrict__ y,
                                                     int npass) {
    constexpr float D[8][8] = {
        { C4,  C4,  C4,  C4,  C4,  C4,  C4,  C4},
        { A1,  A3,  A5,  A7, -A7, -A5, -A3, -A1},
        { B2,  B6, -B6, -B2, -B2, -B6,  B6,  B2},
        { A3, -A7, -A1, -A5,  A5,  A1,  A7, -A3},
        { C4, -C4, -C4,  C4,  C4, -C4, -C4,  C4},
        { A5, -A1,  A7,  A3, -A3, -A7,  A1, -A5},
        { B6, -B2,  B2, -B6, -B6,  B2, -B2,  B6},
        { A7, -A5,  A3, -A1,  A1, -A3,  A5, -A7},
    };

    const int t = blockIdx.x * 256 + threadIdx.x;
    if (t >= npass) return;

    const int h = t & 1;     // 0: cols 0-3, 1: cols 4-7

    // ---- item 0 address ----
    const int g0     = t >> 1;
    const int plane0 = g0 >> 12;     // 4096 blocks per 512x512 plane
    const int b0     = g0 & 4095;
    const size_t base0 = (size_t)plane0 * (IMG_W * IMG_W)
                       + (size_t)(b0 >> 6) * 8 * IMG_W
                       + (size_t)(b0 & 63) * 8 + (size_t)h * 4;

    // ---- item 1 address: block id offset by npass/2 (same h, +48 planes) ----
    const int g1     = g0 + (npass >> 1);
    const int plane1 = g1 >> 12;
    const int b1     = g1 & 4095;
    const size_t base1 = (size_t)plane1 * (IMG_W * IMG_W)
                       + (size_t)(b1 >> 6) * 8 * IMG_W
                       + (size_t)(b1 & 63) * 8 + (size_t)h * 4;

    // ---- issue ALL loads first: 16 x 16B = 256B in flight per thread ----
    const float* __restrict__ s0 = x + base0;
    const float* __restrict__ s1 = x + base1;
    float X0[8][4], X1[8][4];
#pragma unroll
    for (int r = 0; r < 8; ++r) {
        v4f v = *reinterpret_cast<const v4f*>(s0 + (size_t)r * IMG_W);
        X0[r][0] = v.x; X0[r][1] = v.y; X0[r][2] = v.z; X0[r][3] = v.w;
    }
#pragma unroll
    for (int r = 0; r < 8; ++r) {
        v4f v = *reinterpret_cast<const v4f*>(s1 + (size_t)r * IMG_W);
        X1[r][0] = v.x; X1[r][1] = v.y; X1[r][2] = v.z; X1[r][3] = v.w;
    }

    // Per-lane D rows for the row transform (folds to cndmask of literals).
    float Dh[4][8];
#pragma unroll
    for (int jj = 0; jj < 4; ++jj)
#pragma unroll
        for (int m = 0; m < 8; ++m)
            Dh[jj][m] = h ? D[4 + jj][m] : D[jj][m];

    // ================= item 0 =================
    {
        float T[8][4];
#pragma unroll
        for (int i = 0; i < 8; ++i)
#pragma unroll
            for (int k = 0; k < 4; ++k) {
                float s = 0.0f;
#pragma unroll
                for (int r = 0; r < 8; ++r) s = fmaf(D[i][r], X0[r][k], s);
                T[i][k] = s;
            }

        float* __restrict__ dst = y + base0;
#pragma unroll
        for (int i = 0; i < 8; ++i) {
            float r4[4];
#pragma unroll
            for (int kk = 0; kk < 4; ++kk) r4[kk] = __shfl_xor(T[i][kk], 1, 64);
            float lo[4], hi[4];
#pragma unroll
            for (int kk = 0; kk < 4; ++kk) {
                lo[kk] = h ? r4[kk]   : T[i][kk];
                hi[kk] = h ? T[i][kk] : r4[kk];
            }
            float ov[4];
#pragma unroll
            for (int jj = 0; jj < 4; ++jj) {
                float s = 0.0f;
#pragma unroll
                for (int k = 0; k < 4; ++k) s = fmaf(lo[k], Dh[jj][k],     s);
#pragma unroll
                for (int k = 0; k < 4; ++k) s = fmaf(hi[k], Dh[jj][4 + k], s);
                ov[jj] = s;
            }
            v4f o; o.x = ov[0]; o.y = ov[1]; o.z = ov[2]; o.w = ov[3];
            __builtin_nontemporal_store(o, reinterpret_cast<v4f*>(dst + (size_t)i * IMG_W));
        }
    }

    // ================= item 1 =================
    {
        float T[8][4];
#pragma unroll
        for (int i = 0; i < 8; ++i)
#pragma unroll
            for (int k = 0; k < 4; ++k) {
                float s = 0.0f;
#pragma unroll
                for (int r = 0; r < 8; ++r) s = fmaf(D[i][r], X1[r][k], s);
                T[i][k] = s;
            }

        float* __restrict__ dst = y + base1;
#pragma unroll
        for (int i = 0; i < 8; ++i) {
            float r4[4];
#pragma unroll
            for (int kk = 0; kk < 4; ++kk) r4[kk] = __shfl_xor(T[i][kk], 1, 64);
            float lo[4], hi[4];
#pragma unroll
            for (int kk = 0; kk < 4; ++kk) {
                lo[kk] = h ? r4[kk]   : T[i][kk];
                hi[kk] = h ? T[i][kk] : r4[kk];
            }
            float ov[4];
#pragma unroll
            for (int jj = 0; jj < 4; ++jj) {
                float s = 0.0f;
#pragma unroll
                for (int k = 0; k < 4; ++k) s = fmaf(lo[k], Dh[jj][k],     s);
#pragma unroll
                for (int k = 0; k < 4; ++k) s = fmaf(hi[k], Dh[jj][4 + k], s);
                ov[jj] = s;
            }
            v4f o; o.x = ov[0]; o.y = ov[1]; o.z = ov[2]; o.w = ov[3];
            __builtin_nontemporal_store(o, reinterpret_cast<v4f*>(dst + (size_t)i * IMG_W));
        }
    }
}

extern "C" void kernel_launch(void* const* d_in, const int* in_sizes, int n_in,
                              void* d_out, int out_size, void* d_ws, size_t ws_size,
                              hipStream_t stream) {
    const float* x = (const float*)d_in[0];
    float* y = (float*)d_out;

    const int nhalf = out_size / 32;   // 786432 half-blocks (2 per 8x8 block)
    const int npass = nhalf / 2;       // 393216 threads, 2 items each
    const int grid  = npass / 256;     // 1536 WGs

    dct8x8_kernel<<<grid, 256, 0, stream>>>(x, y, npass);
}